// Round 2
// baseline (850.308 us; speedup 1.0000x reference)
//
#include <hip/hip_runtime.h>
#include <stdint.h>

#define NLEV 16
#define LOG2T 19
#define TMASK ((1u << LOG2T) - 1u)
#define PRIME_Y 2654435761u
#define PRIME_Z 805459861u

// Round 1: identical to Round 0 (infra failure, no signal) — baseline resubmit.
// Fused hash-grid encode (16 levels, T=2^19, F=2) + MLP 32->64(relu)->16 + exp(h0).
// One thread per point. Weights are read with wave-uniform indices so the
// compiler emits scalar (s_load) reads -> v_fmac with SGPR operand; no LDS.
__global__ __launch_bounds__(256) void hashmlp_kernel(
    const float* __restrict__ x,
    const float* __restrict__ table,
    const float* __restrict__ W1,
    const float* __restrict__ W2,
    float* __restrict__ out_sig,
    float* __restrict__ out_h,
    int N)
{
    const int i = blockIdx.x * 256 + threadIdx.x;
    if (i >= N) return;

    const float px = x[3 * i + 0];
    const float py = x[3 * i + 1];
    const float pz = x[3 * i + 2];

    // floor(16 * (2^0.4)^l) for l=0..15 (exact-math floors)
    constexpr float RESF[NLEV] = {16.f, 21.f, 27.f, 36.f, 48.f, 64.f, 84.f, 111.f,
                                  147.f, 194.f, 256.f, 337.f, 445.f, 588.f, 776.f, 1024.f};

    float enc[2 * NLEV];

#pragma unroll
    for (int l = 0; l < NLEV; ++l) {
        const float res = RESF[l];
        const float fx = px * res, fy = py * res, fz = pz * res;
        const float gx = floorf(fx), gy = floorf(fy), gz = floorf(fz);
        const float wx = fx - gx, wy = fy - gy, wz = fz - gz;
        const uint32_t ux = (uint32_t)gx, uy = (uint32_t)gy, uz = (uint32_t)gz;
        const uint32_t hy0 = uy * PRIME_Y, hy1 = hy0 + PRIME_Y;  // (uy+1)*P wraps identically
        const uint32_t hz0 = uz * PRIME_Z, hz1 = hz0 + PRIME_Z;
        const uint32_t x0 = ux, x1 = ux + 1u;

        const float2* __restrict__ tab =
            reinterpret_cast<const float2*>(table) + ((size_t)l << LOG2T);

        const float2 c000 = tab[(x0 ^ hy0 ^ hz0) & TMASK];
        const float2 c001 = tab[(x0 ^ hy0 ^ hz1) & TMASK];
        const float2 c010 = tab[(x0 ^ hy1 ^ hz0) & TMASK];
        const float2 c011 = tab[(x0 ^ hy1 ^ hz1) & TMASK];
        const float2 c100 = tab[(x1 ^ hy0 ^ hz0) & TMASK];
        const float2 c101 = tab[(x1 ^ hy0 ^ hz1) & TMASK];
        const float2 c110 = tab[(x1 ^ hy1 ^ hz0) & TMASK];
        const float2 c111 = tab[(x1 ^ hy1 ^ hz1) & TMASK];

        const float ax = 1.f - wx, ay = 1.f - wy, az = 1.f - wz;
        const float w00 = ax * ay, w01 = ax * wy, w10 = wx * ay, w11 = wx * wy;
        const float w000 = w00 * az, w001 = w00 * wz;
        const float w010 = w01 * az, w011 = w01 * wz;
        const float w100 = w10 * az, w101 = w10 * wz;
        const float w110 = w11 * az, w111 = w11 * wz;

        enc[2 * l + 0] = w000 * c000.x + w001 * c001.x + w010 * c010.x + w011 * c011.x +
                         w100 * c100.x + w101 * c101.x + w110 * c110.x + w111 * c111.x;
        enc[2 * l + 1] = w000 * c000.y + w001 * c001.y + w010 * c010.y + w011 * c011.y +
                         w100 * c100.y + w101 * c101.y + w110 * c110.y + w111 * c111.y;
    }

    // MLP: h = (relu(enc @ W1)) @ W2 ; W1 [32,64] row-major, W2 [64,16] row-major.
    float h[16];
#pragma unroll
    for (int o = 0; o < 16; ++o) h[o] = 0.f;

#pragma unroll
    for (int jt = 0; jt < 4; ++jt) {   // tiles of 16 hidden units
        float acc[16];
#pragma unroll
        for (int jj = 0; jj < 16; ++jj) acc[jj] = 0.f;
#pragma unroll
        for (int k = 0; k < 32; ++k) {
            const float e = enc[k];
            const float* __restrict__ wrow = W1 + k * 64 + jt * 16;  // uniform -> s_load
#pragma unroll
            for (int jj = 0; jj < 16; ++jj) acc[jj] = fmaf(e, wrow[jj], acc[jj]);
        }
#pragma unroll
        for (int jj = 0; jj < 16; ++jj) {
            const float a = fmaxf(acc[jj], 0.f);  // relu
            const float* __restrict__ w2row = W2 + (jt * 16 + jj) * 16;  // uniform -> s_load
#pragma unroll
            for (int o = 0; o < 16; ++o) h[o] = fmaf(a, w2row[o], h[o]);
        }
    }

    out_sig[i] = __expf(h[0]);

    float4* __restrict__ oh = reinterpret_cast<float4*>(out_h + (size_t)i * 16);
#pragma unroll
    for (int q = 0; q < 4; ++q)
        oh[q] = make_float4(h[4 * q + 0], h[4 * q + 1], h[4 * q + 2], h[4 * q + 3]);
}

extern "C" void kernel_launch(void* const* d_in, const int* in_sizes, int n_in,
                              void* d_out, int out_size, void* d_ws, size_t ws_size,
                              hipStream_t stream) {
    const float* x     = (const float*)d_in[0];  // [N,3]
    const float* table = (const float*)d_in[1];  // [16, 2^19, 2]
    const float* W1    = (const float*)d_in[2];  // [32,64]
    const float* W2    = (const float*)d_in[3];  // [64,16]

    const int N = in_sizes[0] / 3;
    float* out_sig = (float*)d_out;        // [N]
    float* out_h   = (float*)d_out + N;    // [N,16]

    const int block = 256;
    const int grid = (N + block - 1) / block;
    hashmlp_kernel<<<grid, block, 0, stream>>>(x, table, W1, W2, out_sig, out_h, N);
}

// Round 3
// 762.718 us; speedup vs baseline: 1.1148x; 1.1148x over previous
//
#include <hip/hip_runtime.h>
#include <stdint.h>

#define NLEV 16
#define LOG2T 19
#define TMASK ((1u << LOG2T) - 1u)
#define PRIME_Y 2654435761u
#define PRIME_Z 805459861u

// floor(16 * (2^0.4)^l) for l=0..15 (exact-math floors)
__constant__ float RESF_D[NLEV] = {16.f, 21.f, 27.f, 36.f, 48.f, 64.f, 84.f, 111.f,
                                   147.f, 194.f, 256.f, 337.f, 445.f, 588.f, 776.f, 1024.f};

// ---------------------------------------------------------------------------
// Encode kernel: one thread per (point, level). Two passes; within a pass each
// XCD (blockIdx % 8, round-robin dispatch) handles exactly ONE level, so that
// level's active table set (<= 4 MB) is L2-resident on that XCD.
//   pass 0: levels {6,7,8,9,10,11,12,13}   (the full-table hashed levels)
//   pass 1: levels {14,15,0,1,2,3,4,5}     (2 big + 6 small, all sets <= 4 MB)
// enc layout: [level][N] float2 so wave writes are 512B contiguous.
// ---------------------------------------------------------------------------
__global__ __launch_bounds__(256) void encode_pass_kernel(
    const float* __restrict__ x,
    const float* __restrict__ table,
    float2* __restrict__ enc,
    int N, int pass)
{
    const int slot  = blockIdx.x & 7;
    const int chunk = blockIdx.x >> 3;
    const int level = (pass == 0) ? (6 + slot)
                                  : ((slot < 2) ? (14 + slot) : (slot - 2));

    const int p = chunk * 256 + threadIdx.x;
    if (p >= N) return;

    const float res = RESF_D[level];
    const float fx = x[3 * p + 0] * res;
    const float fy = x[3 * p + 1] * res;
    const float fz = x[3 * p + 2] * res;
    const float gx = floorf(fx), gy = floorf(fy), gz = floorf(fz);
    const float wx = fx - gx, wy = fy - gy, wz = fz - gz;

    const uint32_t ux = (uint32_t)gx, uy = (uint32_t)gy, uz = (uint32_t)gz;
    const uint32_t hy0 = uy * PRIME_Y, hy1 = hy0 + PRIME_Y;
    const uint32_t hz0 = uz * PRIME_Z, hz1 = hz0 + PRIME_Z;
    const uint32_t x0 = ux, x1 = ux + 1u;

    const float2* __restrict__ tab =
        reinterpret_cast<const float2*>(table) + ((size_t)level << LOG2T);

    // Issue all 8 gathers before any use (deep MLP).
    const float2 c000 = tab[(x0 ^ hy0 ^ hz0) & TMASK];
    const float2 c001 = tab[(x0 ^ hy0 ^ hz1) & TMASK];
    const float2 c010 = tab[(x0 ^ hy1 ^ hz0) & TMASK];
    const float2 c011 = tab[(x0 ^ hy1 ^ hz1) & TMASK];
    const float2 c100 = tab[(x1 ^ hy0 ^ hz0) & TMASK];
    const float2 c101 = tab[(x1 ^ hy0 ^ hz1) & TMASK];
    const float2 c110 = tab[(x1 ^ hy1 ^ hz0) & TMASK];
    const float2 c111 = tab[(x1 ^ hy1 ^ hz1) & TMASK];

    const float ax = 1.f - wx, ay = 1.f - wy, az = 1.f - wz;
    const float w00 = ax * ay, w01 = ax * wy, w10 = wx * ay, w11 = wx * wy;
    const float w000 = w00 * az, w001 = w00 * wz;
    const float w010 = w01 * az, w011 = w01 * wz;
    const float w100 = w10 * az, w101 = w10 * wz;
    const float w110 = w11 * az, w111 = w11 * wz;

    float2 e;
    e.x = w000 * c000.x + w001 * c001.x + w010 * c010.x + w011 * c011.x +
          w100 * c100.x + w101 * c101.x + w110 * c110.x + w111 * c111.x;
    e.y = w000 * c000.y + w001 * c001.y + w010 * c010.y + w011 * c011.y +
          w100 * c100.y + w101 * c101.y + w110 * c110.y + w111 * c111.y;

    enc[(size_t)level * N + p] = e;
}

// ---------------------------------------------------------------------------
// MLP kernel: one thread per point. enc reads are wave-contiguous (512B per
// level). Weights read with wave-uniform indices -> s_load -> v_fmac v,s,v.
// ---------------------------------------------------------------------------
__global__ __launch_bounds__(256) void mlp_kernel(
    const float2* __restrict__ enc,
    const float* __restrict__ W1,
    const float* __restrict__ W2,
    float* __restrict__ out_sig,
    float* __restrict__ out_h,
    int N)
{
    const int p = blockIdx.x * 256 + threadIdx.x;
    if (p >= N) return;

    float e[2 * NLEV];
#pragma unroll
    for (int l = 0; l < NLEV; ++l) {
        const float2 v = enc[(size_t)l * N + p];
        e[2 * l + 0] = v.x;
        e[2 * l + 1] = v.y;
    }

    float h[16];
#pragma unroll
    for (int o = 0; o < 16; ++o) h[o] = 0.f;

#pragma unroll
    for (int jt = 0; jt < 4; ++jt) {
        float acc[16];
#pragma unroll
        for (int jj = 0; jj < 16; ++jj) acc[jj] = 0.f;
#pragma unroll
        for (int k = 0; k < 32; ++k) {
            const float ek = e[k];
            const float* __restrict__ wrow = W1 + k * 64 + jt * 16;
#pragma unroll
            for (int jj = 0; jj < 16; ++jj) acc[jj] = fmaf(ek, wrow[jj], acc[jj]);
        }
#pragma unroll
        for (int jj = 0; jj < 16; ++jj) {
            const float a = fmaxf(acc[jj], 0.f);
            const float* __restrict__ w2row = W2 + (jt * 16 + jj) * 16;
#pragma unroll
            for (int o = 0; o < 16; ++o) h[o] = fmaf(a, w2row[o], h[o]);
        }
    }

    out_sig[p] = __expf(h[0]);
    float4* __restrict__ oh = reinterpret_cast<float4*>(out_h + (size_t)p * 16);
#pragma unroll
    for (int q = 0; q < 4; ++q)
        oh[q] = make_float4(h[4 * q + 0], h[4 * q + 1], h[4 * q + 2], h[4 * q + 3]);
}

// ---------------------------------------------------------------------------
// Fallback: Round-0 fused kernel (used only if ws_size < 128 MB).
// ---------------------------------------------------------------------------
__global__ __launch_bounds__(256) void hashmlp_fused_kernel(
    const float* __restrict__ x,
    const float* __restrict__ table,
    const float* __restrict__ W1,
    const float* __restrict__ W2,
    float* __restrict__ out_sig,
    float* __restrict__ out_h,
    int N)
{
    const int i = blockIdx.x * 256 + threadIdx.x;
    if (i >= N) return;

    const float px = x[3 * i + 0];
    const float py = x[3 * i + 1];
    const float pz = x[3 * i + 2];

    constexpr float RESF[NLEV] = {16.f, 21.f, 27.f, 36.f, 48.f, 64.f, 84.f, 111.f,
                                  147.f, 194.f, 256.f, 337.f, 445.f, 588.f, 776.f, 1024.f};
    float enc[2 * NLEV];

#pragma unroll
    for (int l = 0; l < NLEV; ++l) {
        const float res = RESF[l];
        const float fx = px * res, fy = py * res, fz = pz * res;
        const float gx = floorf(fx), gy = floorf(fy), gz = floorf(fz);
        const float wx = fx - gx, wy = fy - gy, wz = fz - gz;
        const uint32_t ux = (uint32_t)gx, uy = (uint32_t)gy, uz = (uint32_t)gz;
        const uint32_t hy0 = uy * PRIME_Y, hy1 = hy0 + PRIME_Y;
        const uint32_t hz0 = uz * PRIME_Z, hz1 = hz0 + PRIME_Z;
        const uint32_t x0 = ux, x1 = ux + 1u;

        const float2* __restrict__ tab =
            reinterpret_cast<const float2*>(table) + ((size_t)l << LOG2T);

        const float2 c000 = tab[(x0 ^ hy0 ^ hz0) & TMASK];
        const float2 c001 = tab[(x0 ^ hy0 ^ hz1) & TMASK];
        const float2 c010 = tab[(x0 ^ hy1 ^ hz0) & TMASK];
        const float2 c011 = tab[(x0 ^ hy1 ^ hz1) & TMASK];
        const float2 c100 = tab[(x1 ^ hy0 ^ hz0) & TMASK];
        const float2 c101 = tab[(x1 ^ hy0 ^ hz1) & TMASK];
        const float2 c110 = tab[(x1 ^ hy1 ^ hz0) & TMASK];
        const float2 c111 = tab[(x1 ^ hy1 ^ hz1) & TMASK];

        const float ax = 1.f - wx, ay = 1.f - wy, az = 1.f - wz;
        const float w00 = ax * ay, w01 = ax * wy, w10 = wx * ay, w11 = wx * wy;
        const float w000 = w00 * az, w001 = w00 * wz;
        const float w010 = w01 * az, w011 = w01 * wz;
        const float w100 = w10 * az, w101 = w10 * wz;
        const float w110 = w11 * az, w111 = w11 * wz;

        enc[2 * l + 0] = w000 * c000.x + w001 * c001.x + w010 * c010.x + w011 * c011.x +
                         w100 * c100.x + w101 * c101.x + w110 * c110.x + w111 * c111.x;
        enc[2 * l + 1] = w000 * c000.y + w001 * c001.y + w010 * c010.y + w011 * c011.y +
                         w100 * c100.y + w101 * c101.y + w110 * c110.y + w111 * c111.y;
    }

    float h[16];
#pragma unroll
    for (int o = 0; o < 16; ++o) h[o] = 0.f;

#pragma unroll
    for (int jt = 0; jt < 4; ++jt) {
        float acc[16];
#pragma unroll
        for (int jj = 0; jj < 16; ++jj) acc[jj] = 0.f;
#pragma unroll
        for (int k = 0; k < 32; ++k) {
            const float ek = enc[k];
            const float* __restrict__ wrow = W1 + k * 64 + jt * 16;
#pragma unroll
            for (int jj = 0; jj < 16; ++jj) acc[jj] = fmaf(ek, wrow[jj], acc[jj]);
        }
#pragma unroll
        for (int jj = 0; jj < 16; ++jj) {
            const float a = fmaxf(acc[jj], 0.f);
            const float* __restrict__ w2row = W2 + (jt * 16 + jj) * 16;
#pragma unroll
            for (int o = 0; o < 16; ++o) h[o] = fmaf(a, w2row[o], h[o]);
        }
    }

    out_sig[i] = __expf(h[0]);
    float4* __restrict__ oh = reinterpret_cast<float4*>(out_h + (size_t)i * 16);
#pragma unroll
    for (int q = 0; q < 4; ++q)
        oh[q] = make_float4(h[4 * q + 0], h[4 * q + 1], h[4 * q + 2], h[4 * q + 3]);
}

extern "C" void kernel_launch(void* const* d_in, const int* in_sizes, int n_in,
                              void* d_out, int out_size, void* d_ws, size_t ws_size,
                              hipStream_t stream) {
    const float* x     = (const float*)d_in[0];  // [N,3]
    const float* table = (const float*)d_in[1];  // [16, 2^19, 2]
    const float* W1    = (const float*)d_in[2];  // [32,64]
    const float* W2    = (const float*)d_in[3];  // [64,16]

    const int N = in_sizes[0] / 3;
    float* out_sig = (float*)d_out;        // [N]
    float* out_h   = (float*)d_out + N;    // [N,16]

    const size_t enc_bytes = (size_t)NLEV * (size_t)N * sizeof(float2);

    if (ws_size >= enc_bytes) {
        float2* enc = (float2*)d_ws;
        const int chunks = (N + 255) / 256;
        const dim3 egrid(8 * chunks);
        encode_pass_kernel<<<egrid, 256, 0, stream>>>(x, table, enc, N, 0);
        encode_pass_kernel<<<egrid, 256, 0, stream>>>(x, table, enc, N, 1);
        mlp_kernel<<<chunks, 256, 0, stream>>>(enc, W1, W2, out_sig, out_h, N);
    } else {
        const int grid = (N + 255) / 256;
        hashmlp_fused_kernel<<<grid, 256, 0, stream>>>(x, table, W1, W2, out_sig, out_h, N);
    }
}